// Round 1
// baseline (232.654 us; speedup 1.0000x reference)
//
#include <hip/hip_runtime.h>

// Problem constants (from reference: M, B, D = 32, 64, 8192)
#define Mh 32
#define Bh 64
#define Dh 8192
#define KCH 1024          // K-range per workgroup in gram kernel
#define NCH (Dh / KCH)    // 8 chunks

// Workspace layout (float offsets). Total ~557 KB.
#define OFF_WSY 0                       // [64][32][32]  Wsy[i][j] = s_i . y_j
#define OFF_WYY (64 * 1024)             // [64][32][32]  Wyy[i][j] = y_i . y_j
#define OFF_VS  (2 * 64 * 1024)         // [64][32]      vs[i] = s_i . frc
#define OFF_VY  (OFF_VS + 64 * 32)      // [64][32]      vy[i] = y_i . frc
#define OFF_CY  (OFF_VY + 64 * 32)      // [64][32]      g * a_i
#define OFF_CS  (OFF_CY + 64 * 32)      // [64][32]      b_i - a_i
#define OFF_G   (OFF_CS + 64 * 32)      // [64]          g per batch
#define WS_ZERO_FLOATS OFF_CY           // region that must be zeroed (atomics)

// ---------------------------------------------------------------------------
// Kernel A: batched Gram matrices. grid = 64 b x 8 k-chunks, 256 threads.
// LDS-staged 32x64 tiles with XOR-4 swizzle; 4x4 register tiles on an 8x8
// thread grid; 4 waves split the 64-wide K stage 16 each.
// ---------------------------------------------------------------------------
__global__ __launch_bounds__(256) void gram_kernel(
    const float* __restrict__ s, const float* __restrict__ y,
    const float* __restrict__ frc, float* __restrict__ ws)
{
    __shared__ float sT[32 * 64];
    __shared__ float yT[32 * 64];
    __shared__ float fT[64];

    const int b  = blockIdx.x & 63;
    const int ch = blockIdx.x >> 6;
    const int k0 = ch * KCH;
    const int t  = threadIdx.x;
    const int w  = t >> 6;        // wave 0..3
    const int l  = t & 63;
    const int tx = l & 7;         // y-row group (cols of Wsy)
    const int ty = l >> 3;        // s-row group (rows of Wsy)

    float asy[4][4] = {};
    float ayy[4][4] = {};
    float avs[4] = {}, avy[4] = {};

    // staging thread -> (i, k4) mapping, two reps cover 32x16 float4s
    const int i0 = t >> 4,          k4_0 = t & 15;
    const int i1 = (t + 256) >> 4,  k4_1 = (t + 256) & 15;

    for (int st = 0; st < KCH / 64; ++st) {
        const int kb = k0 + st * 64;
        // global loads first (overlap with previous stage's compute)
        const float4 sv0 = *(const float4*)(s + ((size_t)i0 * Bh + b) * Dh + kb + (k4_0 << 2));
        const float4 yv0 = *(const float4*)(y + ((size_t)i0 * Bh + b) * Dh + kb + (k4_0 << 2));
        const float4 sv1 = *(const float4*)(s + ((size_t)i1 * Bh + b) * Dh + kb + (k4_1 << 2));
        const float4 yv1 = *(const float4*)(y + ((size_t)i1 * Bh + b) * Dh + kb + (k4_1 << 2));
        float4 fv4 = make_float4(0.f, 0.f, 0.f, 0.f);
        if (t < 16) fv4 = *(const float4*)(frc + (size_t)b * Dh + kb + (t << 2));

        __syncthreads();   // prior compute done before overwriting LDS
        {
            const int kk0 = (k4_0 << 2) ^ (((i0 >> 2) & 7) << 2);
            *(float4*)&sT[i0 * 64 + kk0] = sv0;
            *(float4*)&yT[i0 * 64 + kk0] = yv0;
            const int kk1 = (k4_1 << 2) ^ (((i1 >> 2) & 7) << 2);
            *(float4*)&sT[i1 * 64 + kk1] = sv1;
            *(float4*)&yT[i1 * 64 + kk1] = yv1;
            if (t < 16) *(float4*)&fT[t << 2] = fv4;
        }
        __syncthreads();

        // wave w handles k in [16w, 16w+16)
        #pragma unroll
        for (int kk = 0; kk < 16; kk += 4) {
            const int kc = (w << 4) + kk;
            float4 sv[4], ytv[4], yxv[4];
            #pragma unroll
            for (int aa = 0; aa < 4; ++aa) {
                sv[aa]  = *(const float4*)&sT[((ty << 2) + aa) * 64 + (kc ^ (ty << 2))];
                ytv[aa] = *(const float4*)&yT[((ty << 2) + aa) * 64 + (kc ^ (ty << 2))];
                yxv[aa] = *(const float4*)&yT[((tx << 2) + aa) * 64 + (kc ^ (tx << 2))];
            }
            const float4 fv = *(const float4*)&fT[kc];
            #pragma unroll
            for (int aa = 0; aa < 4; ++aa) {
                #pragma unroll
                for (int cc = 0; cc < 4; ++cc) {
                    asy[aa][cc] += sv[aa].x * yxv[cc].x + sv[aa].y * yxv[cc].y
                                 + sv[aa].z * yxv[cc].z + sv[aa].w * yxv[cc].w;
                    ayy[aa][cc] += ytv[aa].x * yxv[cc].x + ytv[aa].y * yxv[cc].y
                                 + ytv[aa].z * yxv[cc].z + ytv[aa].w * yxv[cc].w;
                }
                avs[aa] += sv[aa].x * fv.x + sv[aa].y * fv.y + sv[aa].z * fv.z + sv[aa].w * fv.w;
                avy[aa] += ytv[aa].x * fv.x + ytv[aa].y * fv.y + ytv[aa].z * fv.z + ytv[aa].w * fv.w;
            }
        }
    }

    // cross-wave reduction (reuse sT for sy, yT for yy, fT for vs/vy)
    __syncthreads();
    for (int wv = 0; wv < 4; ++wv) {
        if (w == wv) {
            #pragma unroll
            for (int aa = 0; aa < 4; ++aa) {
                #pragma unroll
                for (int cc = 0; cc < 4; ++cc) {
                    const int e = ((ty << 2) + aa) * 32 + (tx << 2) + cc;
                    if (wv == 0) { sT[e] = asy[aa][cc];  yT[e] = ayy[aa][cc]; }
                    else         { sT[e] += asy[aa][cc]; yT[e] += ayy[aa][cc]; }
                }
                if (tx == 0) {
                    const int i = (ty << 2) + aa;
                    if (wv == 0) { fT[i] = avs[aa];  fT[32 + i] = avy[aa]; }
                    else         { fT[i] += avs[aa]; fT[32 + i] += avy[aa]; }
                }
            }
        }
        __syncthreads();
    }

    float* WSY = ws + OFF_WSY + b * 1024;
    float* WYY = ws + OFF_WYY + b * 1024;
    for (int e = t; e < 1024; e += 256) {
        unsafeAtomicAdd(&WSY[e], sT[e]);
        unsafeAtomicAdd(&WYY[e], yT[e]);
    }
    if (t < 32)      unsafeAtomicAdd(&ws[OFF_VS + b * 32 + t], fT[t]);
    else if (t < 64) unsafeAtomicAdd(&ws[OFF_VY + b * 32 + (t - 32)], fT[t]);
}

// ---------------------------------------------------------------------------
// Kernel B: per-b M=32 recursion on the Gram matrices, f64, one wave per b.
// Lane i owns row i (and column i) of Wsy and row i of Wyy.
// ---------------------------------------------------------------------------
__global__ __launch_bounds__(64) void recur_kernel(float* __restrict__ ws)
{
    const int b    = blockIdx.x;
    const int lane = threadIdx.x;
    const int i    = lane & 31;   // lanes 32..63 mirror 0..31 (writes guarded)

    const float* WSY = ws + OFF_WSY + b * 1024;
    const float* WYY = ws + OFF_WYY + b * 1024;

    float row_sy[32], col_sy[32], row_yy[32];
    #pragma unroll
    for (int j = 0; j < 32; ++j) {
        row_sy[j] = WSY[i * 32 + j];   // s_i . y_j
        col_sy[j] = WSY[j * 32 + i];   // s_j . y_i
        row_yy[j] = WYY[i * 32 + j];   // y_i . y_j
    }

    const double r = 1.0 / (double)row_sy[i];          // 1/(s_i.y_i)
    double acc = -(double)ws[OFF_VS + b * 32 + i];     // s_i.q0 running
    double a_val = 0.0;
    #pragma unroll
    for (int j = 31; j >= 0; --j) {                    // backward scan
        const double aj = __shfl(r, j) * __shfl(acc, j);
        if (i == j) a_val = aj;
        if (i < j)  acc -= aj * (double)row_sy[j];
    }

    const double g = (double)WSY[31 * 32 + 31] / (double)WYY[31 * 32 + 31];

    double u = -(double)ws[OFF_VY + b * 32 + i];       // y_i.q_f0 / g
    #pragma unroll
    for (int j = 0; j < 32; ++j)
        u -= __shfl(a_val, j) * (double)row_yy[j];
    u *= g;

    double tt = u;
    double b_val = 0.0;
    #pragma unroll
    for (int j = 0; j < 32; ++j) {                     // forward scan
        const double bj = __shfl(r, j) * __shfl(tt, j);
        if (i == j) b_val = bj;
        const double dj = __shfl(a_val, j) - bj;
        if (i > j) tt += dj * (double)col_sy[j];
    }

    if (lane < 32) {
        ws[OFF_CY + b * 32 + i] = (float)(g * a_val);
        ws[OFF_CS + b * 32 + i] = (float)(b_val - a_val);
    }
    if (lane == 0) ws[OFF_G + b] = (float)g;
}

// ---------------------------------------------------------------------------
// Kernel C: out[b,d] = g*frc[b,d] + sum_i cy[i]*y[i,b,d] + cs[i]*s[i,b,d]
// grid = 64 b x 8 d-chunks, 256 threads, 1 float4 per thread. Memory-bound.
// ---------------------------------------------------------------------------
__global__ __launch_bounds__(256) void combine_kernel(
    const float* __restrict__ s, const float* __restrict__ y,
    const float* __restrict__ frc, const float* __restrict__ ws,
    float* __restrict__ out)
{
    __shared__ float cy[32], cs[32];
    const int b  = blockIdx.x & 63;
    const int ch = blockIdx.x >> 6;
    const int t  = threadIdx.x;
    if (t < 32) { cy[t] = ws[OFF_CY + b * 32 + t]; cs[t] = ws[OFF_CS + b * 32 + t]; }
    __syncthreads();

    const int d = ch * 1024 + (t << 2);
    const float g = ws[OFF_G + b];
    const float4 fv = *(const float4*)(frc + (size_t)b * Dh + d);
    float4 acc;
    acc.x = g * fv.x; acc.y = g * fv.y; acc.z = g * fv.z; acc.w = g * fv.w;

    #pragma unroll 8
    for (int i = 0; i < 32; ++i) {
        const float4 yv = *(const float4*)(y + ((size_t)i * Bh + b) * Dh + d);
        const float4 sv = *(const float4*)(s + ((size_t)i * Bh + b) * Dh + d);
        const float a1 = cy[i], a2 = cs[i];
        acc.x += a1 * yv.x + a2 * sv.x;
        acc.y += a1 * yv.y + a2 * sv.y;
        acc.z += a1 * yv.z + a2 * sv.z;
        acc.w += a1 * yv.w + a2 * sv.w;
    }
    *(float4*)(out + (size_t)b * Dh + d) = acc;
}

extern "C" void kernel_launch(void* const* d_in, const int* in_sizes, int n_in,
                              void* d_out, int out_size, void* d_ws, size_t ws_size,
                              hipStream_t stream)
{
    const float* s   = (const float*)d_in[0];
    const float* y   = (const float*)d_in[1];
    const float* frc = (const float*)d_in[2];
    float* out = (float*)d_out;
    float* ws  = (float*)d_ws;

    // zero the atomic accumulation region (ws is poisoned before every call)
    hipMemsetAsync(d_ws, 0, (size_t)WS_ZERO_FLOATS * sizeof(float), stream);

    gram_kernel<<<dim3(Bh * NCH), dim3(256), 0, stream>>>(s, y, frc, ws);
    recur_kernel<<<dim3(Bh), dim3(64), 0, stream>>>(ws);
    combine_kernel<<<dim3(Bh * NCH), dim3(256), 0, stream>>>(s, y, frc, ws, out);
}